// Round 7
// baseline (5319.913 us; speedup 1.0000x reference)
//
#include <hip/hip_runtime.h>
#include <math.h>

// LSTM: B=64, T=784, I=1, H=600.
// 200 WGs = 25 cell-groups x 8 batch-groups. Per WG: 24 cells (96 gate-rows)
// x 8 batches; W_hh slice in registers (12 rows x 10 k per lane); h exchanged
// through IF$ (sc0 sc1 data, AGENT-relaxed flags) -- the round-2/4-proven
// protocol. Fused per-poller wait+stage (24 producers, 8 pollers each).
#define BB 64
#define TT 784
#define HH 600
#define KPAD 640        // k padded: lane owns k in [10*lane, 10*lane+10)
#define CG 25           // cell-groups per batch-group
#define CPW 24          // cells per WG -> 96 gate-rows
#define BWD 8           // batches per WG
#define NWG 200
#define BLOCK 512       // 8 waves; wave w owns rows 12w..12w+11
#define LDS_BYTES (84*1024)   // force 1 WG/CU

__device__ __forceinline__ float sigm_f(float v) {
    return 1.f / (1.f + __expf(-v));
}
__device__ __forceinline__ float tanh_f(float v) {
    return 1.f - 2.f / (__expf(2.f * v) + 1.f);
}

__device__ __forceinline__ void stg_bypass(float* p, float v) {
    asm volatile("global_store_dword %0, %1, off sc0 sc1"
                 :: "v"(p), "v"(v) : "memory");
}

// fold CNT*2 partial sums down to CNT across lane-pairs (lane ^ MASK).
// After: slot i holds value (i + CNT*hi_bit) summed over the pair.
template<int MASK, int CNT>
__device__ __forceinline__ void fold(float* v, int lane) {
    const bool hi = (lane & MASK) != 0;
    #pragma unroll
    for (int i = 0; i < CNT; ++i) {
        float send = hi ? v[i] : v[i + CNT];
        float recv = __shfl_xor(send, MASK);
        v[i] = (hi ? v[i + CNT] : v[i]) + recv;
    }
}

extern "C" __global__ void __launch_bounds__(BLOCK, 2)
lstm_main(const float* __restrict__ x, const float* __restrict__ hs0,
          const float* __restrict__ cs0, const float* __restrict__ W_ih,
          const float* __restrict__ W_hh, const float* __restrict__ b_ih,
          const float* __restrict__ b_hh, float* __restrict__ hbuf,
          unsigned int* __restrict__ flags)
{
    extern __shared__ float lds[];
    float* h_lds = lds;                    // [8][640]
    float* g_lds = lds + BWD * KPAD;       // [96 rows][8 b]

    const int wg   = blockIdx.x;
    const int sg   = wg & 7;               // batch-group
    const int cg   = wg >> 3;              // cell-group 0..24
    const int tid  = threadIdx.x;
    const int w    = tid >> 6;             // wave 0..7
    const int lane = tid & 63;
    const int k0   = 10 * lane;            // this lane's k-slice start (h read)
    const int k0c  = (k0 <= HH - 10) ? k0 : (HH - 10);  // clamped (W read)

    // ---- one-time: W_hh rows 12w..12w+11, k [k0c,k0c+10) into registers ----
    // Unconditional clamped loads: lanes with k0>=600 hold garbage W, but
    // their h values come from the zeroed pad -> products are exactly 0.
    // row (0..95) <-> gate g = row/24, local cell c = row%24; cell = 24*cg+c.
    float Wr[12][10];
    #pragma unroll
    for (int r = 0; r < 12; ++r) {
        const int row = 12 * w + r;
        const int g = row / 24, c = row % 24;
        const float* wp = W_hh + ((size_t)g * HH + CPW * cg + c) * HH + k0c;
        #pragma unroll
        for (int j = 0; j < 10; ++j) Wr[r][j] = wp[j];
    }

    // ---- pointwise/poller lane constants (tid<192: c=tid>>3, b=tid&7) ----
    const int pc = tid >> 3, pb = tid & 7;
    const int cell  = CPW * cg + pc;
    const int bglob = BWD * sg + pb;
    float wihv[4], biasv[4], cst = 0.f;
    if (tid < 192) {
        #pragma unroll
        for (int g = 0; g < 4; ++g) {
            const int grow = g * HH + cell;
            wihv[g]  = W_ih[grow];
            biasv[g] = b_ih[grow] + b_hh[grow];
        }
        cst = cs0[(size_t)bglob * HH + cell];
    }

    // ---- init h_lds from hs0 (8 batches x 600) + zero the k-pad ----
    {
        const float4* s4 = (const float4*)(hs0 + (size_t)BWD * sg * HH);
        for (int i = tid; i < BWD * 150; i += BLOCK) {
            const int b = i / 150, col = i - b * 150;
            *(float4*)&h_lds[b * KPAD + 4 * col] = s4[i];
        }
        if (tid < 80) {
            const int b = tid / 10, j = tid - b * 10;
            *(float4*)&h_lds[b * KPAD + HH + 4 * j] =
                make_float4(0.f, 0.f, 0.f, 0.f);
        }
    }
    __syncthreads();

    unsigned int* myflag = &flags[wg * 16];

    for (int t = 0; t < TT; ++t) {
        // x prefetch (cached, read-only)
        float xv = 0.f;
        if (tid < 192) xv = x[(size_t)bglob * TT + t];

        if (t > 0) {
            // ---- fused wait+stage: poller (producer pi, batch pb) ----
            if (tid < 192) {
                const int pi  = tid >> 3;                 // 0..23
                const int pcg = pi + (pi >= cg);          // skip self
                const int pwg = (pcg << 3) | sg;
                const unsigned int* fp = &flags[pwg * 16];
                while (__hip_atomic_load(fp, __ATOMIC_RELAXED,
                                         __HIP_MEMORY_SCOPE_AGENT) < (unsigned)t)
                    __builtin_amdgcn_s_sleep(1);
                // stage this producer's 24 cells for batch pb (6 x float4)
                const float4* src = (const float4*)(hbuf
                    + (size_t)(t & 1) * BB * HH + (size_t)bglob * HH + CPW * pcg);
                float4 r0, r1, r2, r3, r4, r5;
                asm volatile(
                    "global_load_dwordx4 %0, %6, off sc0 sc1\n\t"
                    "global_load_dwordx4 %1, %6, off offset:16 sc0 sc1\n\t"
                    "global_load_dwordx4 %2, %6, off offset:32 sc0 sc1\n\t"
                    "global_load_dwordx4 %3, %6, off offset:48 sc0 sc1\n\t"
                    "global_load_dwordx4 %4, %6, off offset:64 sc0 sc1\n\t"
                    "global_load_dwordx4 %5, %6, off offset:80 sc0 sc1\n\t"
                    "s_waitcnt vmcnt(0)"
                    : "=&v"(r0), "=&v"(r1), "=&v"(r2),
                      "=&v"(r3), "=&v"(r4), "=&v"(r5)
                    : "v"(src) : "memory");
                float4* dst = (float4*)&h_lds[pb * KPAD + CPW * pcg];
                dst[0] = r0; dst[1] = r1; dst[2] = r2;
                dst[3] = r3; dst[4] = r4; dst[5] = r5;
            }
            __syncthreads();
        }

        // ---- GEMV: two passes of 4 batches; acc v[r*4+bi] over k-slice ----
        #pragma unroll
        for (int bp = 0; bp < 2; ++bp) {
            float hvf[4][10];
            #pragma unroll
            for (int bi = 0; bi < 4; ++bi) {
                const float* hb = &h_lds[(4 * bp + bi) * KPAD + k0];
                #pragma unroll
                for (int j5 = 0; j5 < 5; ++j5) {
                    float2 t2 = *(const float2*)(hb + 2 * j5);
                    hvf[bi][2 * j5]     = t2.x;
                    hvf[bi][2 * j5 + 1] = t2.y;
                }
            }
            float v[48];
            #pragma unroll
            for (int i = 0; i < 48; ++i) v[i] = 0.f;
            #pragma unroll
            for (int r = 0; r < 12; ++r)
                #pragma unroll
                for (int j = 0; j < 10; ++j) {
                    const float wv = Wr[r][j];
                    v[r * 4 + 0] = fmaf(wv, hvf[0][j], v[r * 4 + 0]);
                    v[r * 4 + 1] = fmaf(wv, hvf[1][j], v[r * 4 + 1]);
                    v[r * 4 + 2] = fmaf(wv, hvf[2][j], v[r * 4 + 2]);
                    v[r * 4 + 3] = fmaf(wv, hvf[3][j], v[r * 4 + 3]);
                }

            // reduce over 64 lanes: masks 1,2,4,8 fold, 16/32 xor-sum
            fold<1, 24>(v, lane);
            fold<2, 12>(v, lane);
            fold<4, 6>(v, lane);
            fold<8, 3>(v, lane);
            #pragma unroll
            for (int i = 0; i < 3; ++i) {
                v[i] += __shfl_xor(v[i], 16);
                v[i] += __shfl_xor(v[i], 32);
            }
            // writers: lanes 0..15; value id = s + 3*bitrev4(lane)
            if (lane < 16) {
                const int idb = 3 * (((lane & 1) << 3) | (((lane >> 1) & 1) << 2)
                                   | (((lane >> 2) & 1) << 1) | ((lane >> 3) & 1));
                #pragma unroll
                for (int s = 0; s < 3; ++s) {
                    const int id = idb + s;
                    const int r = id >> 2, bi = id & 3;
                    g_lds[(12 * w + r) * BWD + 4 * bp + bi] = v[s];
                }
            }
        }
        __syncthreads();

        // ---- pointwise LSTM update; own h -> LDS, global copy for peers ----
        if (tid < 192) {
            const float gi = g_lds[(0 * CPW + pc) * BWD + pb] + xv * wihv[0] + biasv[0];
            const float gf = g_lds[(1 * CPW + pc) * BWD + pb] + xv * wihv[1] + biasv[1];
            const float gg = g_lds[(2 * CPW + pc) * BWD + pb] + xv * wihv[2] + biasv[2];
            const float go = g_lds[(3 * CPW + pc) * BWD + pb] + xv * wihv[3] + biasv[3];
            const float cn = sigm_f(gf) * cst + sigm_f(gi) * tanh_f(gg);
            cst = cn;
            const float hv = sigm_f(go) * tanh_f(cn);
            h_lds[pb * KPAD + cell] = hv;   // own slice for next step
            stg_bypass(hbuf + (size_t)((t + 1) & 1) * BB * HH
                            + (size_t)bglob * HH + cell, hv);
        }
        asm volatile("s_waitcnt vmcnt(0)" ::: "memory");  // h stores in IF$
        __syncthreads();
        if (tid == 0)
            __hip_atomic_store(myflag, (unsigned)(t + 1), __ATOMIC_RELAXED,
                               __HIP_MEMORY_SCOPE_AGENT);
    }
}

// final projection: out[b,o] = h_T[b,:] @ W_out[o,:] + b_out[o]
extern "C" __global__ void lstm_out(const float* __restrict__ hbuf0,
                                    const float* __restrict__ W_out,
                                    const float* __restrict__ b_out,
                                    float* __restrict__ out)
{
    int b = blockIdx.x;
    int lane = threadIdx.x;
    float acc[10] = {};
    for (int k = lane; k < HH; k += 64) {
        float hv = hbuf0[(size_t)b * HH + k];
        #pragma unroll
        for (int o = 0; o < 10; ++o)
            acc[o] += hv * W_out[(size_t)o * HH + k];
    }
    #pragma unroll
    for (int o = 0; o < 10; ++o) {
        float v = acc[o];
        for (int off = 32; off > 0; off >>= 1) v += __shfl_down(v, off);
        if (lane == 0) out[b * 10 + o] = v + b_out[o];
    }
}

extern "C" void kernel_launch(void* const* d_in, const int* in_sizes, int n_in,
                              void* d_out, int out_size, void* d_ws, size_t ws_size,
                              hipStream_t stream)
{
    const float* x     = (const float*)d_in[0];
    const float* hs0   = (const float*)d_in[1];
    const float* cs0   = (const float*)d_in[2];
    const float* W_ih  = (const float*)d_in[3];
    const float* W_hh  = (const float*)d_in[4];
    const float* b_ih  = (const float*)d_in[5];
    const float* b_hh  = (const float*)d_in[6];
    const float* W_out = (const float*)d_in[7];
    const float* b_out = (const float*)d_in[8];
    float* out = (float*)d_out;

    // ws: hbuf[2][64][600] f32 | flags[200*16] u32
    float* hbuf = (float*)d_ws;
    unsigned int* flags = (unsigned int*)((char*)d_ws + (size_t)2 * BB * HH * sizeof(float));

    hipFuncSetAttribute((const void*)lstm_main,
                        hipFuncAttributeMaxDynamicSharedMemorySize, LDS_BYTES);

    hipMemsetAsync(flags, 0, NWG * 16 * sizeof(unsigned int), stream);
    hipLaunchKernelGGL(lstm_main, dim3(NWG), dim3(BLOCK), LDS_BYTES, stream,
                       x, hs0, cs0, W_ih, W_hh, b_ih, b_hh, hbuf, flags);
    // t=783 writes hbuf[(784)&1] = hbuf[0]
    hipLaunchKernelGGL(lstm_out, dim3(BB), dim3(64), 0, stream,
                       hbuf, W_out, b_out, out);
}

// Round 8
// 4358.899 us; speedup vs baseline: 1.2205x; 1.2205x over previous
//
#include <hip/hip_runtime.h>
#include <math.h>

// LSTM: B=64, T=784, I=1, H=600.
// Round-4 base (proven: 4.3ms, 0 bank conflicts) + ONE change: W_hh values
// are pinned into VGPRs via opaque asm (compiler was rematerializing them
// from global every GEMV iteration; r4 VGPR_Count=108 < the 120 W floats).
// 200 WGs = 50 cell-groups x 4 batch-groups. 12 cells x 16 batches per WG.
#define BB 64
#define TT 784
#define HH 600
#define CG 50           // cell-groups
#define SGN 4           // batch-groups
#define CPW 12          // cells per WG  -> 48 gate-rows
#define BW 16           // batches per WG
#define NWG (CG*SGN)    // 200
#define BLOCK 512       // 8 waves; wave owns 6 gate-rows; lane=(bh:2 x kh:32)
#define HB4 (BW*150)    // 2400 float4 of h per WG
#define LDS_BYTES (84*1024)   // force 1 WG/CU

typedef float f4v __attribute__((ext_vector_type(4)));

__device__ __forceinline__ float dot4acc(f4v a, float4 b, float acc) {
    acc = fmaf(a[0], b.x, acc);
    acc = fmaf(a[1], b.y, acc);
    acc = fmaf(a[2], b.z, acc);
    acc = fmaf(a[3], b.w, acc);
    return acc;
}

// five pipelined cache-bypassing 16B loads (one IF$ latency)
__device__ __forceinline__ void ldg5_bypass(const float4* g0, const float4* g1,
                                            const float4* g2, const float4* g3,
                                            const float4* g4,
                                            float4& a, float4& b, float4& c,
                                            float4& d, float4& e) {
    asm volatile(
        "global_load_dwordx4 %0, %5, off sc0 sc1\n\t"
        "global_load_dwordx4 %1, %6, off sc0 sc1\n\t"
        "global_load_dwordx4 %2, %7, off sc0 sc1\n\t"
        "global_load_dwordx4 %3, %8, off sc0 sc1\n\t"
        "global_load_dwordx4 %4, %9, off sc0 sc1\n\t"
        "s_waitcnt vmcnt(0)"
        : "=&v"(a), "=&v"(b), "=&v"(c), "=&v"(d), "=&v"(e)
        : "v"(g0), "v"(g1), "v"(g2), "v"(g3), "v"(g4)
        : "memory");
}

__device__ __forceinline__ void stg_bypass(float* p, float v) {
    asm volatile("global_store_dword %0, %1, off sc0 sc1"
                 :: "v"(p), "v"(v) : "memory");
}

__device__ __forceinline__ float sigm_f(float v) {
    return 1.f / (1.f + __expf(-v));
}
__device__ __forceinline__ float tanh_f(float v) {
    return 1.f - 2.f / (__expf(2.f * v) + 1.f);
}

// fold CNT*2 partial sums down to CNT across lane-pairs (kh ^ MASK).
// After the call, slot i holds value (i + CNT*hi_bit) summed over the pair.
template<int MASK, int CNT>
__device__ __forceinline__ void fold(float* v, int kh) {
    const bool hi = (kh & MASK) != 0;
    #pragma unroll
    for (int i = 0; i < CNT; ++i) {
        float send = hi ? v[i] : v[i + CNT];
        float recv = __shfl_xor(send, MASK);
        v[i] = (hi ? v[i + CNT] : v[i]) + recv;
    }
}

extern "C" __global__ void __launch_bounds__(BLOCK, 2)
lstm_main(const float* __restrict__ x, const float* __restrict__ hs0,
          const float* __restrict__ cs0, const float* __restrict__ W_ih,
          const float* __restrict__ W_hh, const float* __restrict__ b_ih,
          const float* __restrict__ b_hh, float* __restrict__ hbuf,
          unsigned int* __restrict__ flags)
{
    extern __shared__ float lds[];
    float4* h4l  = (float4*)lds;          // [2400] = [16 b][150 f4], no pad
    float*  g_lds = lds + 4 * HB4;        // [48 rows][16 b] gate sums

    const int wg   = blockIdx.x;
    const int cg   = wg % CG;             // cell-group
    const int sg   = wg / CG;             // batch-group
    const int tid  = threadIdx.x;
    const int w    = tid >> 6;            // wave 0..7
    const int lane = tid & 63;
    const int bh   = lane >> 5;           // batch half (0: b0-7, 1: b8-15)
    const int kh   = lane & 31;           // k-chunk id (20 floats each)
    const int khc  = (kh < 30) ? kh : 29; // clamp idle lanes to valid addrs
    const int b0   = sg * BW;

    // ---- one-time: W_hh rows 6w..6w+5, k-chunk khc*20..+19 into registers ----
    // row r (0..47) <-> (gate g = r/12, local cell c = r%12), cell = cg*12+c.
    f4v Wr[6][5];
    #pragma unroll
    for (int r = 0; r < 6; ++r) {
        const int row = 6 * w + r;
        const int g   = row / 12, c = row % 12;
        const float* wrow = W_hh + ((size_t)g * HH + cg * CPW + c) * HH + khc * 20;
        #pragma unroll
        for (int j = 0; j < 5; ++j) {
            f4v z = {0.f, 0.f, 0.f, 0.f};
            Wr[r][j] = (kh < 30) ? *(const f4v*)(wrow + 4 * j) : z;
        }
    }
    // PIN: opaque asm makes Wr values non-rematerializable -> must stay in VGPRs.
    #pragma unroll
    for (int r = 0; r < 6; ++r) {
        asm volatile("" : "+v"(Wr[r][0]), "+v"(Wr[r][1]), "+v"(Wr[r][2]),
                          "+v"(Wr[r][3]), "+v"(Wr[r][4]));
    }

    // ---- pointwise-lane constants (tid<192 owns (cell c=tid>>4, batch b=tid&15)) ----
    float wihv[4], biasv[4], cst = 0.f;
    const int pc = tid >> 4, pb = tid & 15;
    const int cell = cg * CPW + pc;            // valid when tid<192
    const int bglob = b0 + pb;
    if (tid < 192) {
        #pragma unroll
        for (int g = 0; g < 4; ++g) {
            const int grow = g * HH + cell;
            wihv[g]  = W_ih[grow];
            biasv[g] = b_ih[grow] + b_hh[grow];
        }
        cst = cs0[(size_t)bglob * HH + cell];
    }

    // stage indices (linear in both src and LDS): f4 idx = b*150 + col
    const int i0 = tid, i1 = tid + 512, i2 = tid + 1024, i3 = tid + 1536;
    const int i4 = (tid + 2048 < HB4) ? tid + 2048 : HB4 - 1;

    unsigned int* myflag = &flags[wg * 16];

    for (int t = 0; t < TT; ++t) {
        // x prefetch (cached, read-only)
        float xv = 0.f;
        if (tid < 192) xv = x[(size_t)bglob * TT + t];

        // ---- wait for all 50 producers of our batch-group (sleep-backoff) ----
        if (t > 0) {
            if (tid < CG) {
                const unsigned int* f = &flags[(sg * CG + tid) * 16];
                while (__hip_atomic_load(f, __ATOMIC_RELAXED,
                                         __HIP_MEMORY_SCOPE_AGENT) < (unsigned)t)
                    __builtin_amdgcn_s_sleep(1);
            }
        }
        __syncthreads();

        // ---- stage h[16][600] -> LDS via 5 pipelined IF$-bypass loads ----
        {
            const float* hsrc = (t == 0) ? hs0 : (hbuf + (size_t)(t & 1) * BB * HH);
            const float4* s4 = (const float4*)hsrc + (size_t)b0 * 150;
            float4 v0, v1, v2, v3, v4;
            ldg5_bypass(s4 + i0, s4 + i1, s4 + i2, s4 + i3, s4 + i4,
                        v0, v1, v2, v3, v4);
            h4l[i0] = v0; h4l[i1] = v1; h4l[i2] = v2; h4l[i3] = v3; h4l[i4] = v4;
        }
        __syncthreads();

        // ---- GEMV: v[r*8+bi] = sum over this lane's 20-k slice, 8 batches ----
        float v[48];
        #pragma unroll
        for (int i = 0; i < 48; ++i) v[i] = 0.f;
        {
            const float4* hb_base = h4l + (size_t)bh * 8 * 150 + khc * 5;
            #pragma unroll
            for (int bi = 0; bi < 8; ++bi) {
                const float4* hb = hb_base + bi * 150;
                const float4 h0 = hb[0], h1 = hb[1], h2 = hb[2],
                             h3 = hb[3], hv4 = hb[4];
                #pragma unroll
                for (int r = 0; r < 6; ++r) {
                    float a = v[r * 8 + bi];
                    a = dot4acc(Wr[r][0], h0, a);
                    a = dot4acc(Wr[r][1], h1, a);
                    a = dot4acc(Wr[r][2], h2, a);
                    a = dot4acc(Wr[r][3], h3, a);
                    a = dot4acc(Wr[r][4], hv4, a);
                    v[r * 8 + bi] = a;
                }
            }
        }

        // ---- folding reduction over the 32 kh-lanes: 48 -> 24 -> 12 -> 6 -> 3 ----
        fold<16, 24>(v, kh);
        fold<8, 12>(v, kh);
        fold<4, 6>(v, kh);
        fold<2, 3>(v, kh);
        #pragma unroll
        for (int i = 0; i < 3; ++i)
            v[i] += __shfl_xor(v[i], 1);

        // ---- gather: even-kh lanes write their 3 final sums ----
        // value id = 3*(kh>>1)+s = rowl*8+bi  (rowl 0..5, bi 0..7)
        if (!(kh & 1)) {
            const int vb = 3 * (kh >> 1);
            #pragma unroll
            for (int s = 0; s < 3; ++s) {
                const int val = vb + s;
                const int rowl = val >> 3, bi = val & 7;
                g_lds[(6 * w + rowl) * 16 + bh * 8 + bi] = v[s];
            }
        }
        __syncthreads();

        // ---- pointwise LSTM cell update (192 lanes) + bypass-store h ----
        float* hdst = hbuf + (size_t)((t + 1) & 1) * BB * HH;
        if (tid < 192) {
            const float gi = g_lds[(0 * 12 + pc) * 16 + pb] + xv * wihv[0] + biasv[0];
            const float gf = g_lds[(1 * 12 + pc) * 16 + pb] + xv * wihv[1] + biasv[1];
            const float gg = g_lds[(2 * 12 + pc) * 16 + pb] + xv * wihv[2] + biasv[2];
            const float go = g_lds[(3 * 12 + pc) * 16 + pb] + xv * wihv[3] + biasv[3];
            const float cn = sigm_f(gf) * cst + sigm_f(gi) * tanh_f(gg);
            cst = cn;
            stg_bypass(&hdst[(size_t)bglob * HH + cell], sigm_f(go) * tanh_f(cn));
        }
        asm volatile("s_waitcnt vmcnt(0)" ::: "memory");
        __syncthreads();   // all waves' h stores are in IF$ before flag
        if (tid == 0)
            __hip_atomic_store(myflag, (unsigned)(t + 1), __ATOMIC_RELAXED,
                               __HIP_MEMORY_SCOPE_AGENT);
    }
}

// final projection: out[b,o] = h_T[b,:] @ W_out[o,:] + b_out[o]
extern "C" __global__ void lstm_out(const float* __restrict__ hbuf0,
                                    const float* __restrict__ W_out,
                                    const float* __restrict__ b_out,
                                    float* __restrict__ out)
{
    int b = blockIdx.x;
    int lane = threadIdx.x;
    float acc[10] = {};
    for (int k = lane; k < HH; k += 64) {
        float hv = hbuf0[(size_t)b * HH + k];
        #pragma unroll
        for (int o = 0; o < 10; ++o)
            acc[o] += hv * W_out[(size_t)o * HH + k];
    }
    #pragma unroll
    for (int o = 0; o < 10; ++o) {
        float v = acc[o];
        for (int off = 32; off > 0; off >>= 1) v += __shfl_down(v, off);
        if (lane == 0) out[b * 10 + o] = v + b_out[o];
    }
}

extern "C" void kernel_launch(void* const* d_in, const int* in_sizes, int n_in,
                              void* d_out, int out_size, void* d_ws, size_t ws_size,
                              hipStream_t stream)
{
    const float* x     = (const float*)d_in[0];
    const float* hs0   = (const float*)d_in[1];
    const float* cs0   = (const float*)d_in[2];
    const float* W_ih  = (const float*)d_in[3];
    const float* W_hh  = (const float*)d_in[4];
    const float* b_ih  = (const float*)d_in[5];
    const float* b_hh  = (const float*)d_in[6];
    const float* W_out = (const float*)d_in[7];
    const float* b_out = (const float*)d_in[8];
    float* out = (float*)d_out;

    // workspace: hbuf[2][64][600] f32, then flags[200] spaced 64 B
    float* hbuf = (float*)d_ws;
    unsigned int* flags = (unsigned int*)((char*)d_ws + (size_t)2 * BB * HH * sizeof(float));

    hipFuncSetAttribute((const void*)lstm_main,
                        hipFuncAttributeMaxDynamicSharedMemorySize, LDS_BYTES);

    hipMemsetAsync(flags, 0, NWG * 16 * sizeof(unsigned int), stream);
    hipLaunchKernelGGL(lstm_main, dim3(NWG), dim3(BLOCK), LDS_BYTES, stream,
                       x, hs0, cs0, W_ih, W_hh, b_ih, b_hh, hbuf, flags);
    // t=783 writes hbuf[(784)&1] = hbuf[0]
    hipLaunchKernelGGL(lstm_out, dim3(BB), dim3(64), 0, stream,
                       hbuf, W_out, b_out, out);
}